// Round 1
// baseline (531.017 us; speedup 1.0000x reference)
//
#include <hip/hip_runtime.h>
#include <hip/hip_cooperative_groups.h>
#include <stdint.h>

namespace cg = cooperative_groups;

#define NB_LAYERS 4
#define KSIZE 5
#define BSZ 8
#define LIN 2048
#define LSEQ 2049
#define CCH 32
#define HCH 16
#define MROWS (BSZ*LSEQ)          // 16392
#define NTILES ((MROWS+15)/16)    // 1025
#define KDIM 576                  // 512 (h*c) + 32 (k3b block) + 32 (skip block)
#define NEG 0.1f
#define BNEPS 1e-5f
#define GRID 205
#define BLOCK 320                 // 5 waves -> 205*5 = 1025 waves = NTILES
#define NTHREADS (GRID*BLOCK)     // 65600

typedef _Float16 h2v __attribute__((ext_vector_type(2)));
typedef _Float16 h8v __attribute__((ext_vector_type(8)));
typedef float    f4v __attribute__((ext_vector_type(4)));

union H8 { h8v v; h2v h[4]; };

static __device__ __forceinline__ h2v mkh2(float a, float b) {
  h2v r; r[0] = (_Float16)a; r[1] = (_Float16)b; return r;
}

struct CParams {
  const float* etimes; const int* types; const float* emb;
  const float* k1W; const float* k1b; const float* k2W; const float* k2b;
  const float* k3W; const float* k3b; const float* skipW;
  const float* gamma; const float* beta;
  float* enc_a; float* enc_b; float* stats; int* blockmax;
  _Float16* Wt; float* out;
};

static __device__ __forceinline__ void gsync(cg::grid_group& g) {
  __threadfence();   // release: push enc/stats out of this XCD's L2
  g.sync();
  __threadfence();   // acquire: invalidate stale L1/L2 lines before re-reading ping-pong bufs
}

// ---------------- fused cont-conv layer: taps + MLP + MFMA GEMM + BN-stats ----------------
// FUSE_BN: apply previous layer's BN + leaky-relu on every gathered input element.
template<bool FUSE_BN>
static __device__ __forceinline__ void conv_layer(const CParams& P,
    const float* __restrict__ enc_in, float* __restrict__ enc_out,
    int layer, int dil, float* sst)
{
  if (threadIdx.x < 64) sst[threadIdx.x] = 0.f;
  __syncthreads();

  const int lane = threadIdx.x & 63;
  const int wv   = threadIdx.x >> 6;
  const int m    = lane & 15;     // A-frag row within tile / B-frag col n
  const int q    = lane >> 4;     // quad: k-subchunk + feat channels q*8..q*8+7

  const float* k1Wp = P.k1W + layer * HCH;
  const float* k1bp = P.k1b + layer * HCH;
  const float* k2Wp = P.k2W + layer * HCH * HCH;
  const float* k2bp = P.k2b + layer * HCH;
  const _Float16* Wt = P.Wt + (size_t)layer * CCH * KDIM;
  float* stats_out = P.stats + layer * 64;
  const float* etimes = P.etimes;

  float k1w[HCH], k1b[HCH], k2b[HCH];
#pragma unroll
  for (int h = 0; h < HCH; h++) { k1w[h] = k1Wp[h]; k1b[h] = k1bp[h]; k2b[h] = k2bp[h]; }

  // BN of previous layer, fused into loads: x -> leaky(x*sc + ob)
  float sc8[8], ob8[8];
  if (FUSE_BN) {
    const float* st = P.stats + (layer - 1) * 64;
    const float* gm = P.gamma + (layer - 1) * CCH;
    const float* bt = P.beta  + (layer - 1) * CCH;
    const float inv = 1.f / (float)MROWS;
#pragma unroll
    for (int j = 0; j < 8; j++) {
      int c = q * 8 + j;
      float mu = st[c] * inv;
      float var = st[32 + c] * inv - mu * mu;
      float sc = gm[c] * rsqrtf(var + BNEPS);
      sc8[j] = sc; ob8[j] = bt[c] - mu * sc;
    }
  }

  const _Float16* wb0 = Wt + m * KDIM + q * 8;
  const _Float16* wb1 = Wt + (m + 16) * KDIM + q * 8;

  const int tile = blockIdx.x * (BLOCK / 64) + wv;   // in [0, NTILES): exactly one tile per wave
  {
    int row = tile * 16 + m;
    bool rvalid = row < MROWS;
    int rowc = min(row, MROWS - 1);
    int b = rowc / LSEQ, pos = rowc % LSEQ;
    float t_l = (pos == 0) ? 0.f : etimes[b * LIN + pos - 1];
    bool mask_l = rvalid && (t_l != 0.f);

    h2v wh[KSIZE][8];     // g * h2  (fp16 pairs)
    h2v fh[KSIZE][4];     // gathered feats (fp16 pairs)
    h2v fself[4];
    float Fb[8];
#pragma unroll
    for (int jj = 0; jj < 8; jj++) Fb[jj] = 0.f;

#pragma unroll
    for (int tap = 0; tap < KSIZE; tap++) {
      int j = pos - tap * dil;
      int jc = max(j, 0);
      float t_j = (jc == 0) ? 0.f : etimes[b * LIN + jc - 1];
      bool gm = mask_l && (j >= 0) && (t_j != 0.f);
      float dt = gm ? (t_l - t_j) : 0.f;

      const float* fp = enc_in + (b * LSEQ + jc) * CCH + q * 8;
      float4 fA = *(const float4*)(fp);
      float4 fB = *(const float4*)(fp + 4);
      float fv[8] = {fA.x, fA.y, fA.z, fA.w, fB.x, fB.y, fB.z, fB.w};
      if (FUSE_BN) {
#pragma unroll
        for (int jj = 0; jj < 8; jj++) {
          float x = fmaf(fv[jj], sc8[jj], ob8[jj]);
          fv[jj] = fmaxf(x, NEG * x);
        }
      }

      if (tap == 0) {
        float rv = rvalid ? 1.f : 0.f;
#pragma unroll
        for (int p2 = 0; p2 < 4; p2++) fself[p2] = mkh2(fv[2*p2] * rv, fv[2*p2+1] * rv);
      }
      float g = gm ? 1.f : 0.f;
#pragma unroll
      for (int jj = 0; jj < 8; jj++) Fb[jj] += g * fv[jj];
#pragma unroll
      for (int p2 = 0; p2 < 4; p2++) fh[tap][p2] = mkh2(fv[2*p2], fv[2*p2+1]);

      if (__ballot(gm)) {
        float h1[HCH];
#pragma unroll
        for (int h = 0; h < HCH; h++) { float x = fmaf(dt, k1w[h], k1b[h]); h1[h] = fmaxf(x, NEG * x); }
        float h2[HCH];
#pragma unroll
        for (int h = 0; h < HCH; h++) h2[h] = k2b[h];
#pragma unroll
        for (int hp = 0; hp < HCH; hp++) {
          float hv = h1[hp];
#pragma unroll
          for (int h = 0; h < HCH; h++) h2[h] = fmaf(hv, k2Wp[hp * HCH + h], h2[h]);
        }
#pragma unroll
        for (int hh = 0; hh < 8; hh++) {
          float a = h2[2*hh];     a = fmaxf(a, NEG * a) * g;
          float c2 = h2[2*hh+1];  c2 = fmaxf(c2, NEG * c2) * g;
          wh[tap][hh] = mkh2(a, c2);
        }
      } else {
#pragma unroll
        for (int hh = 0; hh < 8; hh++) wh[tap][hh] = mkh2(0.f, 0.f);
      }
    }

    f4v acc0 = {0.f, 0.f, 0.f, 0.f};
    f4v acc1 = {0.f, 0.f, 0.f, 0.f};

#pragma unroll
    for (int ks = 0; ks < 16; ks++) {
      H8 bf0, bf1, af;
      bf0.v = *(const h8v*)(wb0 + ks * 32);
      bf1.v = *(const h8v*)(wb1 + ks * 32);
      h2v u0 = mkh2(0.f,0.f), u1 = mkh2(0.f,0.f), u2 = mkh2(0.f,0.f), u3 = mkh2(0.f,0.f);
#pragma unroll
      for (int tap = 0; tap < KSIZE; tap++) {
        _Float16 w = wh[tap][ks >> 1][ks & 1];
        h2v wd; wd[0] = w; wd[1] = w;
        u0 += wd * fh[tap][0];
        u1 += wd * fh[tap][1];
        u2 += wd * fh[tap][2];
        u3 += wd * fh[tap][3];
      }
      af.h[0] = u0; af.h[1] = u1; af.h[2] = u2; af.h[3] = u3;
      acc0 = __builtin_amdgcn_mfma_f32_16x16x32_f16(af.v, bf0.v, acc0, 0, 0, 0);
      acc1 = __builtin_amdgcn_mfma_f32_16x16x32_f16(af.v, bf1.v, acc1, 0, 0, 0);
    }
    { // k3b block (k = 512..543)
      H8 bf0, bf1, af;
      bf0.v = *(const h8v*)(wb0 + 512);
      bf1.v = *(const h8v*)(wb1 + 512);
#pragma unroll
      for (int p2 = 0; p2 < 4; p2++) af.h[p2] = mkh2(Fb[2*p2], Fb[2*p2+1]);
      acc0 = __builtin_amdgcn_mfma_f32_16x16x32_f16(af.v, bf0.v, acc0, 0, 0, 0);
      acc1 = __builtin_amdgcn_mfma_f32_16x16x32_f16(af.v, bf1.v, acc1, 0, 0, 0);
    }
    { // skip block (k = 544..575)
      H8 bf0, bf1, af;
      bf0.v = *(const h8v*)(wb0 + 544);
      bf1.v = *(const h8v*)(wb1 + 544);
      af.h[0] = fself[0]; af.h[1] = fself[1]; af.h[2] = fself[2]; af.h[3] = fself[3];
      acc0 = __builtin_amdgcn_mfma_f32_16x16x32_f16(af.v, bf0.v, acc0, 0, 0, 0);
      acc1 = __builtin_amdgcn_mfma_f32_16x16x32_f16(af.v, bf1.v, acc1, 0, 0, 0);
    }

    // epilogue: store + BN stats.  D layout: col = lane&15, row = (lane>>4)*4 + r
    float s0 = 0.f, s1 = 0.f, s2 = 0.f, s3 = 0.f;
#pragma unroll
    for (int r = 0; r < 4; r++) {
      float v0 = acc0[r], v1 = acc1[r];
      s0 += v0; s1 += v0 * v0; s2 += v1; s3 += v1 * v1;
      int rd = tile * 16 + q * 4 + r;
      if (rd < MROWS) {
        enc_out[rd * CCH + m] = v0;
        enc_out[rd * CCH + 16 + m] = v1;
      }
    }
    s0 += __shfl_xor(s0, 16, 64); s0 += __shfl_xor(s0, 32, 64);
    s1 += __shfl_xor(s1, 16, 64); s1 += __shfl_xor(s1, 32, 64);
    s2 += __shfl_xor(s2, 16, 64); s2 += __shfl_xor(s2, 32, 64);
    s3 += __shfl_xor(s3, 16, 64); s3 += __shfl_xor(s3, 32, 64);
    if (q == 0) {
      atomicAdd(&sst[m], s0);
      atomicAdd(&sst[32 + m], s1);
      atomicAdd(&sst[16 + m], s2);
      atomicAdd(&sst[48 + m], s3);
    }
  }
  __syncthreads();
  if (threadIdx.x < 64) atomicAdd(&stats_out[threadIdx.x], sst[threadIdx.x]);
}

// ---------------- single persistent cooperative kernel ----------------
__global__ __launch_bounds__(BLOCK, 1) void ccnn_kernel(CParams P) {
  __shared__ float sst[64];
  __shared__ int smax[BLOCK / 64];
  cg::grid_group grid = cg::this_grid();

  const int tid = threadIdx.x;
  const int bid = blockIdx.x;
  const int gtid = bid * BLOCK + tid;
  const int lane = tid & 63;
  const int wv = tid >> 6;

  // ---- phase 0a: zero BN stats, per-block type max, build fp16 weight table ----
  if (bid == 0 && tid < NB_LAYERS * 64) P.stats[tid] = 0.f;
  {
    int v = 0;
    if (gtid < BSZ * LIN) v = P.types[gtid];
#pragma unroll
    for (int off = 32; off; off >>= 1) v = max(v, __shfl_xor(v, off, 64));
    if (lane == 0) smax[wv] = v;
  }
  for (int id = gtid; id < NB_LAYERS * CCH * KDIM; id += NTHREADS) {
    int layer = id / (CCH * KDIM);
    int rem = id % (CCH * KDIM);
    int n = rem / KDIM;
    int k = rem % KDIM;
    float val;
    if (k < 512)      { int h = k >> 5, c = k & 31; val = P.k3W[layer*16384 + h*1024 + c*32 + n]; }
    else if (k < 544) { int c = k - 512;            val = P.k3b[layer*1024 + c*32 + n]; }
    else              { int c = k - 544;            val = P.skipW[layer*1024 + c*32 + n]; }
    P.Wt[id] = (_Float16)val;
  }
  __syncthreads();
  if (tid == 0) {
    int v = smax[0];
#pragma unroll
    for (int i = 1; i < BLOCK / 64; i++) v = max(v, smax[i]);
    P.blockmax[bid] = v;
  }
  gsync(grid);

  // ---- phase 0b: embedding lookup -> enc_a ----
  {
    int mx = -1;  // lazy grid-max: only threads touching a BOS row (pos==0) pay the reduce
    for (int id = gtid; id < MROWS * CCH; id += NTHREADS) {
      int row = id >> 5, c = id & 31;
      int b = row / LSEQ, pos = row % LSEQ;
      int t;
      if (pos == 0) {
        if (mx < 0) { mx = 0; for (int i = 0; i < GRID; i++) mx = max(mx, P.blockmax[i]); }
        t = mx + 1;
      } else {
        t = P.types[b * LIN + pos - 1];
      }
      P.enc_a[id] = (t == 0) ? 0.f : P.emb[t * CCH + c];
    }
  }
  gsync(grid);

  // ---- 4 conv layers, BN of layer i fused into layer i+1's loads ----
  conv_layer<false>(P, P.enc_a, P.enc_b, 0, 1, sst);
  gsync(grid);
  conv_layer<true >(P, P.enc_b, P.enc_a, 1, 2, sst);
  gsync(grid);
  conv_layer<true >(P, P.enc_a, P.enc_b, 2, 4, sst);
  gsync(grid);
  conv_layer<true >(P, P.enc_b, P.enc_a, 3, 8, sst);
  gsync(grid);

  // ---- final: BN + leaky of layer 3 -> out ----
  {
    const float* st = P.stats + 3 * 64;
    const int c = gtid & 31;          // NTHREADS % 32 == 0 -> channel constant per thread
    const float inv = 1.f / (float)MROWS;
    float mu = st[c] * inv;
    float var = st[32 + c] * inv - mu * mu;
    float sc = P.gamma[3 * CCH + c] * rsqrtf(var + BNEPS);
    float ob = P.beta[3 * CCH + c] - mu * sc;
    for (int id = gtid; id < MROWS * CCH; id += NTHREADS) {
      float v = fmaf(P.enc_a[id], sc, ob);
      P.out[id] = fmaxf(v, NEG * v);
    }
  }
}

extern "C" void kernel_launch(void* const* d_in, const int* in_sizes, int n_in,
                              void* d_out, int out_size, void* d_ws, size_t ws_size,
                              hipStream_t stream) {
  (void)in_sizes; (void)n_in; (void)out_size; (void)ws_size;
  CParams p;
  p.etimes = (const float*)d_in[0];
  p.types  = (const int*)d_in[1];
  p.emb    = (const float*)d_in[2];
  p.k1W    = (const float*)d_in[3];
  p.k1b    = (const float*)d_in[4];
  p.k2W    = (const float*)d_in[5];
  p.k2b    = (const float*)d_in[6];
  p.k3W    = (const float*)d_in[7];
  p.k3b    = (const float*)d_in[8];
  p.skipW  = (const float*)d_in[9];
  // d_in[10] = skipb: BN-invariant, dropped
  p.gamma  = (const float*)d_in[11];
  p.beta   = (const float*)d_in[12];

  float* enc_a = (float*)d_ws;
  float* enc_b = enc_a + (size_t)MROWS * CCH;
  float* stats = enc_b + (size_t)MROWS * CCH;
  int* blockmax = (int*)(stats + NB_LAYERS * 64);
  _Float16* Wt = (_Float16*)(((uintptr_t)(blockmax + 256) + 255) & ~(uintptr_t)255);

  p.enc_a = enc_a; p.enc_b = enc_b; p.stats = stats; p.blockmax = blockmax;
  p.Wt = Wt; p.out = (float*)d_out;

  void* kargs[] = { (void*)&p };
  hipLaunchCooperativeKernel((const void*)ccnn_kernel, dim3(GRID), dim3(BLOCK),
                             kargs, 0, stream);
}

// Round 2
// 166.672 us; speedup vs baseline: 3.1860x; 3.1860x over previous
//
#include <hip/hip_runtime.h>
#include <stdint.h>

#define NB_LAYERS 4
#define KSIZE 5
#define BSZ 8
#define LIN 2048
#define LSEQ 2049
#define CCH 32
#define HCH 16
#define MROWS (BSZ*LSEQ)          // 16392
#define NTILES ((MROWS+15)/16)    // 1025
#define KDIM 576                  // 512 (h*c) + 32 (k3b block) + 32 (skip block)
#define NEG 0.1f
#define BNEPS 1e-5f
#define NWAVEMAX 256              // (BSZ*LIN)/64

typedef _Float16 h2v __attribute__((ext_vector_type(2)));
typedef _Float16 h8v __attribute__((ext_vector_type(8)));
typedef float    f4v __attribute__((ext_vector_type(4)));

union H8 { h8v v; h2v h[4]; };

static __device__ __forceinline__ h2v mkh2(float a, float b) {
  h2v r; r[0] = (_Float16)a; r[1] = (_Float16)b; return r;
}

// ---------------- setup: zero BN stats + per-wave type max + fp16 weight table ----------------
// grid: 288 x 256  (NB_LAYERS*CCH*KDIM = 73728 = 288*256, one Wt element per thread)
__global__ __launch_bounds__(256) void prep_kernel(
    const float* __restrict__ k3W, const float* __restrict__ k3b,
    const float* __restrict__ skipW, _Float16* __restrict__ Wt,
    const int* __restrict__ types, int* __restrict__ wavemax,
    float* __restrict__ stats) {
  int id = blockIdx.x * blockDim.x + threadIdx.x;

  if (id < NB_LAYERS * 64) stats[id] = 0.f;

  if (id < BSZ * LIN) {
    int v = types[id];
#pragma unroll
    for (int off = 32; off; off >>= 1) v = max(v, __shfl_xor(v, off, 64));
    if ((threadIdx.x & 63) == 0) wavemax[id >> 6] = v;
  }

  {
    int layer = id / (CCH * KDIM);
    int rem = id % (CCH * KDIM);
    int n = rem / KDIM;
    int k = rem % KDIM;
    float val;
    if (k < 512)      { int h = k >> 5, c = k & 31; val = k3W[layer*16384 + h*1024 + c*32 + n]; }
    else if (k < 544) { int c = k - 512;            val = k3b[layer*1024 + c*32 + n]; }
    else              { int c = k - 544;            val = skipW[layer*1024 + c*32 + n]; }
    Wt[id] = (_Float16)val;
  }
}

// ---------------- embedding lookup ----------------
// grid: 2049 x 256  (MROWS*CCH = 524544 = 2049*256)
__global__ __launch_bounds__(256) void embed_kernel(
    const int* __restrict__ types, const float* __restrict__ emb,
    const int* __restrict__ wavemax, float* __restrict__ enc) {
  int id = blockIdx.x * blockDim.x + threadIdx.x;
  int row = id >> 5, c = id & 31;
  int b = row / LSEQ, pos = row % LSEQ;
  int t;
  if (pos == 0) {
    // BOS rows only (8 rows x 32 ch = 256 threads): reduce the 256 per-wave maxes
    const int4* wm = (const int4*)wavemax;
    int mx = 0;
    for (int i = 0; i < NWAVEMAX / 4; i++) {
      int4 v = wm[i];
      mx = max(mx, max(max(v.x, v.y), max(v.z, v.w)));
    }
    t = mx + 1;
  } else {
    t = types[b * LIN + pos - 1];
  }
  enc[id] = (t == 0) ? 0.f : emb[t * CCH + c];
}

// ---------------- fused cont-conv layer: taps + MLP + MFMA GEMM + BN-stats ----------------
// FUSE_BN: apply previous layer's BN + leaky-relu on every gathered input element.
// grid: 257 x 256 -> 1028 waves, exactly one 16-row tile per wave (NTILES=1025).
template<bool FUSE_BN>
__global__ __launch_bounds__(256) void conv_kernel(
    const float* __restrict__ enc_in, float* __restrict__ enc_out,
    const float* __restrict__ etimes,
    const float* __restrict__ k1Wp, const float* __restrict__ k1bp,
    const float* __restrict__ k2Wp, const float* __restrict__ k2bp,
    const _Float16* __restrict__ Wt,      // this layer's 32x576 fp16 table
    const float* __restrict__ stats_prev, float* __restrict__ stats_out,
    const float* __restrict__ gamma_prev, const float* __restrict__ beta_prev,
    int dil)
{
  __shared__ float sst[64];
  if (threadIdx.x < 64) sst[threadIdx.x] = 0.f;
  __syncthreads();

  const int lane = threadIdx.x & 63;
  const int wv   = threadIdx.x >> 6;
  const int m    = lane & 15;     // A-frag row within tile / B-frag col n
  const int q    = lane >> 4;     // quad: k-subchunk + feat channels q*8..q*8+7

  // MLP params (uniform -> scalar regs)
  float k1w[HCH], k1b[HCH], k2b[HCH];
#pragma unroll
  for (int h = 0; h < HCH; h++) { k1w[h] = k1Wp[h]; k1b[h] = k1bp[h]; k2b[h] = k2bp[h]; }

  // BN of previous layer, fused into loads: x -> leaky(x*sc + ob)
  float sc8[8], ob8[8];
  if (FUSE_BN) {
    const float inv = 1.f / (float)MROWS;
#pragma unroll
    for (int j = 0; j < 8; j++) {
      int c = q * 8 + j;
      float mu = stats_prev[c] * inv;
      float var = stats_prev[32 + c] * inv - mu * mu;
      float sc = gamma_prev[c] * rsqrtf(var + BNEPS);
      sc8[j] = sc; ob8[j] = beta_prev[c] - mu * sc;
    }
  }

  const _Float16* wb0 = Wt + m * KDIM + q * 8;
  const _Float16* wb1 = Wt + (m + 16) * KDIM + q * 8;

  const int tile = blockIdx.x * 4 + wv;   // one tile per wave; tiles >= NTILES compute dead rows
  {
    int row = tile * 16 + m;
    bool rvalid = row < MROWS;
    int rowc = min(row, MROWS - 1);
    int b = rowc / LSEQ, pos = rowc % LSEQ;
    float t_l = (pos == 0) ? 0.f : etimes[b * LIN + pos - 1];
    bool mask_l = rvalid && (t_l != 0.f);

    h2v wh[KSIZE][8];     // g * h2  (fp16 pairs)
    h2v fh[KSIZE][4];     // gathered feats (fp16 pairs)
    h2v fself[4];
    float Fb[8];
#pragma unroll
    for (int jj = 0; jj < 8; jj++) Fb[jj] = 0.f;

#pragma unroll
    for (int tap = 0; tap < KSIZE; tap++) {
      int j = pos - tap * dil;
      int jc = max(j, 0);
      float t_j = (jc == 0) ? 0.f : etimes[b * LIN + jc - 1];
      bool gm = mask_l && (j >= 0) && (t_j != 0.f);
      float dt = gm ? (t_l - t_j) : 0.f;

      const float* fp = enc_in + (b * LSEQ + jc) * CCH + q * 8;
      float4 fA = *(const float4*)(fp);
      float4 fB = *(const float4*)(fp + 4);
      float fv[8] = {fA.x, fA.y, fA.z, fA.w, fB.x, fB.y, fB.z, fB.w};
      if (FUSE_BN) {
#pragma unroll
        for (int jj = 0; jj < 8; jj++) {
          float x = fmaf(fv[jj], sc8[jj], ob8[jj]);
          fv[jj] = fmaxf(x, NEG * x);
        }
      }

      if (tap == 0) {
        float rv = rvalid ? 1.f : 0.f;
#pragma unroll
        for (int p2 = 0; p2 < 4; p2++) fself[p2] = mkh2(fv[2*p2] * rv, fv[2*p2+1] * rv);
      }
      float g = gm ? 1.f : 0.f;
#pragma unroll
      for (int jj = 0; jj < 8; jj++) Fb[jj] += g * fv[jj];
#pragma unroll
      for (int p2 = 0; p2 < 4; p2++) fh[tap][p2] = mkh2(fv[2*p2], fv[2*p2+1]);

      if (__ballot(gm)) {
        float h1[HCH];
#pragma unroll
        for (int h = 0; h < HCH; h++) { float x = fmaf(dt, k1w[h], k1b[h]); h1[h] = fmaxf(x, NEG * x); }
        float h2[HCH];
#pragma unroll
        for (int h = 0; h < HCH; h++) h2[h] = k2b[h];
#pragma unroll
        for (int hp = 0; hp < HCH; hp++) {
          float hv = h1[hp];
#pragma unroll
          for (int h = 0; h < HCH; h++) h2[h] = fmaf(hv, k2Wp[hp * HCH + h], h2[h]);
        }
#pragma unroll
        for (int hh = 0; hh < 8; hh++) {
          float a = h2[2*hh];     a = fmaxf(a, NEG * a) * g;
          float c2 = h2[2*hh+1];  c2 = fmaxf(c2, NEG * c2) * g;
          wh[tap][hh] = mkh2(a, c2);
        }
      } else {
#pragma unroll
        for (int hh = 0; hh < 8; hh++) wh[tap][hh] = mkh2(0.f, 0.f);
      }
    }

    f4v acc0 = {0.f, 0.f, 0.f, 0.f};
    f4v acc1 = {0.f, 0.f, 0.f, 0.f};

#pragma unroll
    for (int ks = 0; ks < 16; ks++) {
      H8 bf0, bf1, af;
      bf0.v = *(const h8v*)(wb0 + ks * 32);
      bf1.v = *(const h8v*)(wb1 + ks * 32);
      h2v u0 = mkh2(0.f,0.f), u1 = mkh2(0.f,0.f), u2 = mkh2(0.f,0.f), u3 = mkh2(0.f,0.f);
#pragma unroll
      for (int tap = 0; tap < KSIZE; tap++) {
        _Float16 w = wh[tap][ks >> 1][ks & 1];
        h2v wd; wd[0] = w; wd[1] = w;
        u0 += wd * fh[tap][0];
        u1 += wd * fh[tap][1];
        u2 += wd * fh[tap][2];
        u3 += wd * fh[tap][3];
      }
      af.h[0] = u0; af.h[1] = u1; af.h[2] = u2; af.h[3] = u3;
      acc0 = __builtin_amdgcn_mfma_f32_16x16x32_f16(af.v, bf0.v, acc0, 0, 0, 0);
      acc1 = __builtin_amdgcn_mfma_f32_16x16x32_f16(af.v, bf1.v, acc1, 0, 0, 0);
    }
    { // k3b block (k = 512..543)
      H8 bf0, bf1, af;
      bf0.v = *(const h8v*)(wb0 + 512);
      bf1.v = *(const h8v*)(wb1 + 512);
#pragma unroll
      for (int p2 = 0; p2 < 4; p2++) af.h[p2] = mkh2(Fb[2*p2], Fb[2*p2+1]);
      acc0 = __builtin_amdgcn_mfma_f32_16x16x32_f16(af.v, bf0.v, acc0, 0, 0, 0);
      acc1 = __builtin_amdgcn_mfma_f32_16x16x32_f16(af.v, bf1.v, acc1, 0, 0, 0);
    }
    { // skip block (k = 544..575)
      H8 bf0, bf1, af;
      bf0.v = *(const h8v*)(wb0 + 544);
      bf1.v = *(const h8v*)(wb1 + 544);
      af.h[0] = fself[0]; af.h[1] = fself[1]; af.h[2] = fself[2]; af.h[3] = fself[3];
      acc0 = __builtin_amdgcn_mfma_f32_16x16x32_f16(af.v, bf0.v, acc0, 0, 0, 0);
      acc1 = __builtin_amdgcn_mfma_f32_16x16x32_f16(af.v, bf1.v, acc1, 0, 0, 0);
    }

    // epilogue: store + BN stats.  D layout: col = lane&15, row = (lane>>4)*4 + r
    float s0 = 0.f, s1 = 0.f, s2 = 0.f, s3 = 0.f;
#pragma unroll
    for (int r = 0; r < 4; r++) {
      float v0 = acc0[r], v1 = acc1[r];
      s0 += v0; s1 += v0 * v0; s2 += v1; s3 += v1 * v1;
      int rd = tile * 16 + q * 4 + r;
      if (rd < MROWS) {
        enc_out[rd * CCH + m] = v0;
        enc_out[rd * CCH + 16 + m] = v1;
      }
    }
    s0 += __shfl_xor(s0, 16, 64); s0 += __shfl_xor(s0, 32, 64);
    s1 += __shfl_xor(s1, 16, 64); s1 += __shfl_xor(s1, 32, 64);
    s2 += __shfl_xor(s2, 16, 64); s2 += __shfl_xor(s2, 32, 64);
    s3 += __shfl_xor(s3, 16, 64); s3 += __shfl_xor(s3, 32, 64);
    if (q == 0) {
      atomicAdd(&sst[m], s0);
      atomicAdd(&sst[32 + m], s1);
      atomicAdd(&sst[16 + m], s2);
      atomicAdd(&sst[48 + m], s3);
    }
  }
  __syncthreads();
  if (threadIdx.x < 64) atomicAdd(&stats_out[threadIdx.x], sst[threadIdx.x]);
}

// ---------------- final BN + leaky-relu ----------------
// grid: 2049 x 256
__global__ __launch_bounds__(256) void bn_kernel(
    const float* __restrict__ x, float* __restrict__ out,
    const float* __restrict__ stats,
    const float* __restrict__ gamma, const float* __restrict__ beta) {
  int id = blockIdx.x * blockDim.x + threadIdx.x;
  int c = id & 31;
  const float inv = 1.f / (float)MROWS;
  float mu = stats[c] * inv;
  float var = stats[32 + c] * inv - mu * mu;
  float sc = gamma[c] * rsqrtf(var + BNEPS);
  float v = fmaf(x[id], sc, beta[c] - mu * sc);
  out[id] = fmaxf(v, NEG * v);
}

extern "C" void kernel_launch(void* const* d_in, const int* in_sizes, int n_in,
                              void* d_out, int out_size, void* d_ws, size_t ws_size,
                              hipStream_t stream) {
  (void)in_sizes; (void)n_in; (void)out_size; (void)ws_size;
  const float* event_times = (const float*)d_in[0];
  const int*   event_types = (const int*)d_in[1];
  const float* emb   = (const float*)d_in[2];
  const float* k1W   = (const float*)d_in[3];
  const float* k1b   = (const float*)d_in[4];
  const float* k2W   = (const float*)d_in[5];
  const float* k2b   = (const float*)d_in[6];
  const float* k3W   = (const float*)d_in[7];
  const float* k3b   = (const float*)d_in[8];
  const float* skipW = (const float*)d_in[9];
  // d_in[10] = skipb: BN-invariant, dropped
  const float* gamma = (const float*)d_in[11];
  const float* beta  = (const float*)d_in[12];

  float* enc_a = (float*)d_ws;
  float* enc_b = enc_a + (size_t)MROWS * CCH;
  float* stats = enc_b + (size_t)MROWS * CCH;
  int*   wavemax = (int*)(stats + NB_LAYERS * 64);
  _Float16* Wt = (_Float16*)(((uintptr_t)(wavemax + NWAVEMAX) + 255) & ~(uintptr_t)255);

  prep_kernel<<<288, 256, 0, stream>>>(k3W, k3b, skipW, Wt, event_types, wavemax, stats);
  embed_kernel<<<2049, 256, 0, stream>>>(event_types, emb, wavemax, enc_a);

  // layer 0 (no BN fusion on input)
  conv_kernel<false><<<257, 256, 0, stream>>>(enc_a, enc_b, event_times,
      k1W, k1b, k2W, k2b, Wt, nullptr, stats, nullptr, nullptr, 1);
  // layers 1..3: fuse BN+leaky of previous layer into gather loads
  const int dils[NB_LAYERS] = {1, 2, 4, 8};
  const float* bufs[2] = {enc_a, enc_b};
  for (int i = 1; i < NB_LAYERS; i++) {
    const float* cin = bufs[i & 1];        // layer1: enc_b, layer2: enc_a, layer3: enc_b
    float* cout = (float*)bufs[(i + 1) & 1];
    conv_kernel<true><<<257, 256, 0, stream>>>(cin, cout, event_times,
        k1W + i * HCH, k1b + i * HCH, k2W + i * HCH * HCH, k2b + i * HCH,
        Wt + (size_t)i * CCH * KDIM,
        stats + (i - 1) * 64, stats + i * 64,
        gamma + (i - 1) * CCH, beta + (i - 1) * CCH, dils[i]);
  }
  // final BN+leaky of layer 3 (output sits in enc_a after 4 layers)
  bn_kernel<<<2049, 256, 0, stream>>>(enc_a, (float*)d_out,
      stats + 3 * 64, gamma + 3 * CCH, beta + 3 * CCH);
}

// Round 3
// 152.425 us; speedup vs baseline: 3.4838x; 1.0935x over previous
//
#include <hip/hip_runtime.h>
#include <stdint.h>

#define NB_LAYERS 4
#define KSIZE 5
#define BSZ 8
#define LIN 2048
#define LSEQ 2049
#define CCH 32
#define HCH 16
#define MROWS (BSZ*LSEQ)          // 16392
#define NTILES ((MROWS+15)/16)    // 1025
#define KDIM 576                  // 512 (h*c) + 32 (k3b block) + 32 (skip block)
#define NEG 0.1f
#define BNEPS 1e-5f
#define NWAVEMAX 256              // (BSZ*LIN)/64
#define CONVGRID 205
#define CONVBLK 320               // 5 waves * 205 blocks = 1025 waves = NTILES, <=1 block/CU

typedef _Float16 h2v __attribute__((ext_vector_type(2)));
typedef _Float16 h8v __attribute__((ext_vector_type(8)));
typedef float    f4v __attribute__((ext_vector_type(4)));

union H8 { h8v v; h2v h[4]; };

static __device__ __forceinline__ h2v mkh2(float a, float b) {
  h2v r; r[0] = (_Float16)a; r[1] = (_Float16)b; return r;
}

// ---------------- setup: zero BN stats + per-wave type max + fp16 weight table ----------------
// grid: 288 x 256  (NB_LAYERS*CCH*KDIM = 73728 = 288*256, one Wt element per thread)
__global__ __launch_bounds__(256) void prep_kernel(
    const float* __restrict__ k3W, const float* __restrict__ k3b,
    const float* __restrict__ skipW, _Float16* __restrict__ Wt,
    const int* __restrict__ types, int* __restrict__ wavemax,
    float* __restrict__ stats) {
  int id = blockIdx.x * blockDim.x + threadIdx.x;

  if (id < NB_LAYERS * 64) stats[id] = 0.f;

  if (id < BSZ * LIN) {
    int v = types[id];
#pragma unroll
    for (int off = 32; off; off >>= 1) v = max(v, __shfl_xor(v, off, 64));
    if ((threadIdx.x & 63) == 0) wavemax[id >> 6] = v;
  }

  {
    int layer = id / (CCH * KDIM);
    int rem = id % (CCH * KDIM);
    int n = rem / KDIM;
    int k = rem % KDIM;
    float val;
    if (k < 512)      { int h = k >> 5, c = k & 31; val = k3W[layer*16384 + h*1024 + c*32 + n]; }
    else if (k < 544) { int c = k - 512;            val = k3b[layer*1024 + c*32 + n]; }
    else              { int c = k - 544;            val = skipW[layer*1024 + c*32 + n]; }
    Wt[id] = (_Float16)val;
  }
}

// ---------------- fused cont-conv layer ----------------
// MODE 0: layer-0, input = embedding lookup fused at gather time.
// MODE 1: layers 1-3, input = enc_in with previous layer's BN+leaky fused.
// Per wave: one 16-row tile.  Phases:
//   G: gather taps (fh/fself/Fb) in (row=m, ch-quad=q) lane role
//   M: 80 (row,tap) MLP jobs over 64 lanes x 1.25 passes, weights from LDS, results -> LDS
//   U: read wh back, pack A-frags, 38 MFMAs, store + BN-stats
template<int MODE>
__global__ __launch_bounds__(CONVBLK) void conv_kernel(
    const float* __restrict__ enc_in,
    const int*   __restrict__ types,
    const float* __restrict__ emb,
    const int*   __restrict__ wavemax,
    float* __restrict__ enc_out,
    const float* __restrict__ etimes,
    const float* __restrict__ k1Wp, const float* __restrict__ k1bp,
    const float* __restrict__ k2Wp, const float* __restrict__ k2bp,
    const _Float16* __restrict__ Wt,      // this layer's 32x576 fp16 table
    const float* __restrict__ stats_prev, float* __restrict__ stats_out,
    const float* __restrict__ gamma_prev, const float* __restrict__ beta_prev,
    int dil)
{
  __shared__ float sst[64];
  __shared__ alignas(16) float sW[304];          // k1w[16] k1b[16] k2b[16] k2W[256]
  __shared__ h8v swh[CONVBLK/64 * KSIZE * 16 * 2]; // per-wave MLP results: [wv][tap][row][16 halves]

  const int tid  = threadIdx.x;
  const int lane = tid & 63;
  const int wv   = tid >> 6;
  const int m    = lane & 15;     // A-frag row within tile / B-frag col n
  const int q    = lane >> 4;     // quad: k-subchunk + feat channels q*8..q*8+7

  // ---- stage MLP weights + zero stats scratch ----
  if (tid < 64) sst[tid] = 0.f;
  if (tid < 16) { sW[tid] = k1Wp[tid]; sW[16 + tid] = k1bp[tid]; sW[32 + tid] = k2bp[tid]; }
  if (tid >= 64 && tid < 64 + 256) sW[48 + tid - 64] = k2Wp[tid - 64];
  __syncthreads();

  // BN of previous layer, fused into loads: x -> leaky(x*sc + ob)
  float sc8[8], ob8[8];
  if (MODE == 1) {
    const float inv = 1.f / (float)MROWS;
#pragma unroll
    for (int j = 0; j < 8; j++) {
      int c = q * 8 + j;
      float mu = stats_prev[c] * inv;
      float var = stats_prev[32 + c] * inv - mu * mu;
      float sc = gamma_prev[c] * rsqrtf(var + BNEPS);
      sc8[j] = sc; ob8[j] = beta_prev[c] - mu * sc;
    }
  }

  const _Float16* wb0 = Wt + m * KDIM + q * 8;
  const _Float16* wb1 = Wt + (m + 16) * KDIM + q * 8;

  const int tile = blockIdx.x * (CONVBLK / 64) + wv;   // exactly one tile per wave
  int row = tile * 16 + m;
  bool rvalid = row < MROWS;
  int rowc = min(row, MROWS - 1);
  int b = rowc / LSEQ, pos = rowc % LSEQ;
  float t_l = (pos == 0) ? 0.f : etimes[b * LIN + pos - 1];
  bool mask_l = rvalid && (t_l != 0.f);

  // BOS embedding row index (only conv0, only waves containing a pos==0 row)
  int bosv = 0;
  if (MODE == 0) {
    if (__ballot(pos == 0)) {
      const int4* wm = (const int4*)wavemax;
      int mx = 0;
#pragma unroll 4
      for (int i = 0; i < NWAVEMAX / 4; i++) {
        int4 v = wm[i];
        mx = max(mx, max(max(v.x, v.y), max(v.z, v.w)));
      }
      bosv = mx + 1;
    }
  }

  // ---- phase G: gather taps ----
  h2v fh[KSIZE][4];     // gathered feats (fp16 pairs)
  h2v fself[4];
  float Fb[8];
#pragma unroll
  for (int jj = 0; jj < 8; jj++) Fb[jj] = 0.f;

#pragma unroll
  for (int tap = 0; tap < KSIZE; tap++) {
    int j = pos - tap * dil;
    int jc = max(j, 0);
    float t_j = (jc == 0) ? 0.f : etimes[b * LIN + jc - 1];
    bool gm = mask_l && (j >= 0) && (t_j != 0.f);

    float fv[8];
    if (MODE == 0) {
      int tl = 0;
      if (jc > 0) tl = types[b * LIN + jc - 1];
      int t = (jc == 0) ? ((tap == 0) ? bosv : 0) : tl;
      const float* ep = emb + t * CCH + q * 8;
      float4 eA = *(const float4*)(ep);
      float4 eB = *(const float4*)(ep + 4);
      float zf = (t != 0) ? 1.f : 0.f;
      fv[0]=eA.x*zf; fv[1]=eA.y*zf; fv[2]=eA.z*zf; fv[3]=eA.w*zf;
      fv[4]=eB.x*zf; fv[5]=eB.y*zf; fv[6]=eB.z*zf; fv[7]=eB.w*zf;
    } else {
      const float* fp = enc_in + (b * LSEQ + jc) * CCH + q * 8;
      float4 fA = *(const float4*)(fp);
      float4 fB = *(const float4*)(fp + 4);
      fv[0]=fA.x; fv[1]=fA.y; fv[2]=fA.z; fv[3]=fA.w;
      fv[4]=fB.x; fv[5]=fB.y; fv[6]=fB.z; fv[7]=fB.w;
#pragma unroll
      for (int jj = 0; jj < 8; jj++) {
        float x = fmaf(fv[jj], sc8[jj], ob8[jj]);
        fv[jj] = fmaxf(x, NEG * x);
      }
    }

    if (tap == 0) {
      float rv = rvalid ? 1.f : 0.f;
#pragma unroll
      for (int p2 = 0; p2 < 4; p2++) fself[p2] = mkh2(fv[2*p2] * rv, fv[2*p2+1] * rv);
    }
    float g = gm ? 1.f : 0.f;
#pragma unroll
    for (int jj = 0; jj < 8; jj++) Fb[jj] += g * fv[jj];
#pragma unroll
    for (int p2 = 0; p2 < 4; p2++) fh[tap][p2] = mkh2(fv[2*p2], fv[2*p2+1]);
  }

  // ---- phase M: 80 (row,tap) MLP jobs distributed over lanes ----
  // rep 0: lane -> (row = lane&15, tap = lane>>4) covering taps 0..3
  // rep 1: lanes 0..15 -> (row = lane&15, tap = 4)
#pragma unroll
  for (int rep = 0; rep < 2; rep++) {
    const int jt = rep ? (KSIZE - 1) : (lane >> 4);
    const bool act = rep ? (lane < 16) : true;
    int j2 = pos - jt * dil;
    int jc2 = max(j2, 0);
    float tj2 = (jc2 == 0) ? 0.f : etimes[b * LIN + jc2 - 1];
    bool g2 = act && mask_l && (j2 >= 0) && (tj2 != 0.f);
    float dt = g2 ? (t_l - tj2) : 0.f;

    H8 w0, w1;
    if (__ballot(g2)) {
      const f4v* k1wv = (const f4v*)&sW[0];
      const f4v* k1bv = (const f4v*)&sW[16];
      const f4v* k2bv = (const f4v*)&sW[32];
      float h1[HCH], h2[HCH];
#pragma unroll
      for (int h4 = 0; h4 < 4; h4++) {
        f4v cw = k1wv[h4], cb = k1bv[h4], c2 = k2bv[h4];
#pragma unroll
        for (int r = 0; r < 4; r++) {
          float x = fmaf(dt, cw[r], cb[r]);
          h1[h4*4+r] = fmaxf(x, NEG * x);
          h2[h4*4+r] = c2[r];
        }
      }
#pragma unroll
      for (int hp = 0; hp < HCH; hp++) {
        float hv = h1[hp];
        const f4v* kk = (const f4v*)&sW[48 + hp * 16];
#pragma unroll
        for (int h4 = 0; h4 < 4; h4++) {
          f4v c = kk[h4];
#pragma unroll
          for (int r = 0; r < 4; r++) h2[h4*4+r] = fmaf(hv, c[r], h2[h4*4+r]);
        }
      }
      float g = g2 ? 1.f : 0.f;
#pragma unroll
      for (int p2 = 0; p2 < 4; p2++) {
        float a0 = h2[2*p2];     a0 = fmaxf(a0, NEG * a0) * g;
        float a1 = h2[2*p2+1];   a1 = fmaxf(a1, NEG * a1) * g;
        w0.h[p2] = mkh2(a0, a1);
        float b0 = h2[8+2*p2];   b0 = fmaxf(b0, NEG * b0) * g;
        float b1 = h2[8+2*p2+1]; b1 = fmaxf(b1, NEG * b1) * g;
        w1.h[p2] = mkh2(b0, b1);
      }
    } else {
#pragma unroll
      for (int p2 = 0; p2 < 4; p2++) { w0.h[p2] = mkh2(0.f, 0.f); w1.h[p2] = mkh2(0.f, 0.f); }
    }
    if (act) {
      int base = ((wv * KSIZE + jt) * 16 + m) * 2;
      swh[base] = w0.v; swh[base + 1] = w1.v;
    }
  }
  __syncthreads();

  // ---- phase U: read wh, pack A-frags, MFMA ----
  h2v wh[KSIZE][8];
#pragma unroll
  for (int tap = 0; tap < KSIZE; tap++) {
    int base = ((wv * KSIZE + tap) * 16 + m) * 2;
    H8 a0, a1; a0.v = swh[base]; a1.v = swh[base + 1];
#pragma unroll
    for (int p2 = 0; p2 < 4; p2++) { wh[tap][p2] = a0.h[p2]; wh[tap][4+p2] = a1.h[p2]; }
  }

  f4v acc0 = {0.f, 0.f, 0.f, 0.f};
  f4v acc1 = {0.f, 0.f, 0.f, 0.f};

#pragma unroll
  for (int ks = 0; ks < 16; ks++) {
    H8 bf0, bf1, af;
    bf0.v = *(const h8v*)(wb0 + ks * 32);
    bf1.v = *(const h8v*)(wb1 + ks * 32);
    h2v u0 = mkh2(0.f,0.f), u1 = mkh2(0.f,0.f), u2 = mkh2(0.f,0.f), u3 = mkh2(0.f,0.f);
#pragma unroll
    for (int tap = 0; tap < KSIZE; tap++) {
      _Float16 w = wh[tap][ks >> 1][ks & 1];
      h2v wd; wd[0] = w; wd[1] = w;
      u0 += wd * fh[tap][0];
      u1 += wd * fh[tap][1];
      u2 += wd * fh[tap][2];
      u3 += wd * fh[tap][3];
    }
    af.h[0] = u0; af.h[1] = u1; af.h[2] = u2; af.h[3] = u3;
    acc0 = __builtin_amdgcn_mfma_f32_16x16x32_f16(af.v, bf0.v, acc0, 0, 0, 0);
    acc1 = __builtin_amdgcn_mfma_f32_16x16x32_f16(af.v, bf1.v, acc1, 0, 0, 0);
  }
  { // k3b block (k = 512..543)
    H8 bf0, bf1, af;
    bf0.v = *(const h8v*)(wb0 + 512);
    bf1.v = *(const h8v*)(wb1 + 512);
#pragma unroll
    for (int p2 = 0; p2 < 4; p2++) af.h[p2] = mkh2(Fb[2*p2], Fb[2*p2+1]);
    acc0 = __builtin_amdgcn_mfma_f32_16x16x32_f16(af.v, bf0.v, acc0, 0, 0, 0);
    acc1 = __builtin_amdgcn_mfma_f32_16x16x32_f16(af.v, bf1.v, acc1, 0, 0, 0);
  }
  { // skip block (k = 544..575)
    H8 bf0, bf1, af;
    bf0.v = *(const h8v*)(wb0 + 544);
    bf1.v = *(const h8v*)(wb1 + 544);
    af.h[0] = fself[0]; af.h[1] = fself[1]; af.h[2] = fself[2]; af.h[3] = fself[3];
    acc0 = __builtin_amdgcn_mfma_f32_16x16x32_f16(af.v, bf0.v, acc0, 0, 0, 0);
    acc1 = __builtin_amdgcn_mfma_f32_16x16x32_f16(af.v, bf1.v, acc1, 0, 0, 0);
  }

  // epilogue: store + BN stats.  D layout: col = lane&15, row = (lane>>4)*4 + r
  float s0 = 0.f, s1 = 0.f, s2 = 0.f, s3 = 0.f;
#pragma unroll
  for (int r = 0; r < 4; r++) {
    float v0 = acc0[r], v1 = acc1[r];
    s0 += v0; s1 += v0 * v0; s2 += v1; s3 += v1 * v1;
    int rd = tile * 16 + q * 4 + r;
    if (rd < MROWS) {
      enc_out[rd * CCH + m] = v0;
      enc_out[rd * CCH + 16 + m] = v1;
    }
  }
  s0 += __shfl_xor(s0, 16, 64); s0 += __shfl_xor(s0, 32, 64);
  s1 += __shfl_xor(s1, 16, 64); s1 += __shfl_xor(s1, 32, 64);
  s2 += __shfl_xor(s2, 16, 64); s2 += __shfl_xor(s2, 32, 64);
  s3 += __shfl_xor(s3, 16, 64); s3 += __shfl_xor(s3, 32, 64);
  if (q == 0) {
    atomicAdd(&sst[m], s0);
    atomicAdd(&sst[32 + m], s1);
    atomicAdd(&sst[16 + m], s2);
    atomicAdd(&sst[48 + m], s3);
  }
  __syncthreads();
  if (tid < 64) atomicAdd(&stats_out[tid], sst[tid]);
}

// ---------------- final BN + leaky-relu ----------------
// grid: 2049 x 256
__global__ __launch_bounds__(256) void bn_kernel(
    const float* __restrict__ x, float* __restrict__ out,
    const float* __restrict__ stats,
    const float* __restrict__ gamma, const float* __restrict__ beta) {
  int id = blockIdx.x * blockDim.x + threadIdx.x;
  int c = id & 31;
  const float inv = 1.f / (float)MROWS;
  float mu = stats[c] * inv;
  float var = stats[32 + c] * inv - mu * mu;
  float sc = gamma[c] * rsqrtf(var + BNEPS);
  float v = fmaf(x[id], sc, beta[c] - mu * sc);
  out[id] = fmaxf(v, NEG * v);
}

extern "C" void kernel_launch(void* const* d_in, const int* in_sizes, int n_in,
                              void* d_out, int out_size, void* d_ws, size_t ws_size,
                              hipStream_t stream) {
  (void)in_sizes; (void)n_in; (void)out_size; (void)ws_size;
  const float* event_times = (const float*)d_in[0];
  const int*   event_types = (const int*)d_in[1];
  const float* emb   = (const float*)d_in[2];
  const float* k1W   = (const float*)d_in[3];
  const float* k1b   = (const float*)d_in[4];
  const float* k2W   = (const float*)d_in[5];
  const float* k2b   = (const float*)d_in[6];
  const float* k3W   = (const float*)d_in[7];
  const float* k3b   = (const float*)d_in[8];
  const float* skipW = (const float*)d_in[9];
  // d_in[10] = skipb: BN-invariant, dropped
  const float* gamma = (const float*)d_in[11];
  const float* beta  = (const float*)d_in[12];

  float* enc_a = (float*)d_ws;
  float* enc_b = enc_a + (size_t)MROWS * CCH;
  float* stats = enc_b + (size_t)MROWS * CCH;
  int*   wavemax = (int*)(stats + NB_LAYERS * 64);
  _Float16* Wt = (_Float16*)(((uintptr_t)(wavemax + NWAVEMAX) + 255) & ~(uintptr_t)255);

  prep_kernel<<<288, 256, 0, stream>>>(k3W, k3b, skipW, Wt, event_types, wavemax, stats);

  // layer 0: embedding fused into gather
  conv_kernel<0><<<CONVGRID, CONVBLK, 0, stream>>>(
      nullptr, event_types, emb, wavemax, enc_b, event_times,
      k1W, k1b, k2W, k2b, Wt, nullptr, stats, nullptr, nullptr, 1);

  // layers 1..3: previous layer's BN+leaky fused into gather loads
  const int dils[NB_LAYERS] = {1, 2, 4, 8};
  float* bufs[2] = {enc_a, enc_b};
  for (int i = 1; i < NB_LAYERS; i++) {
    const float* cin = bufs[i & 1];        // layer1: enc_b, layer2: enc_a, layer3: enc_b
    float* cout = bufs[(i + 1) & 1];
    conv_kernel<1><<<CONVGRID, CONVBLK, 0, stream>>>(
        cin, nullptr, nullptr, nullptr, cout, event_times,
        k1W + i * HCH, k1b + i * HCH, k2W + i * HCH * HCH, k2b + i * HCH,
        Wt + (size_t)i * CCH * KDIM,
        stats + (i - 1) * 64, stats + i * 64,
        gamma + (i - 1) * CCH, beta + (i - 1) * CCH, dils[i]);
  }
  // final BN+leaky of layer 3 (output sits in enc_a after 4 layers)
  bn_kernel<<<2049, 256, 0, stream>>>(enc_a, (float*)d_out,
      stats + 3 * 64, gamma + 3 * CCH, beta + 3 * CCH);
}